// Round 5
// baseline (387.536 us; speedup 1.0000x reference)
//
#include <hip/hip_runtime.h>
#include <math.h>

#define HID 4096
#define B 32
#define H 32
#define D 128
#define KBLK 16
#define MAXB 64
#define CH 128
#define NCH 8

// out[b][n] = sum_k x[b][k] * W[n][k]
// MODE 0: QKV (grid 3*512; mats 0,1 get fused RoPE, pair-column mapping).
// MODE 1: single matrix, no rope (grid 512).
template <int MODE>
__global__ __launch_bounds__(256) void gemv_kernel(
    const float* __restrict__ W0, const float* __restrict__ W1, const float* __restrict__ W2,
    const float* __restrict__ x, const int* __restrict__ positions, float* __restrict__ out)
{
    __shared__ float wt[8][256];
    __shared__ float buf[4][8][66];   // per-wave transpose-reduce scratch
    const int bid = blockIdx.x;
    const int mat = (MODE == 0) ? (bid >> 9) : 0;
    const int sub = bid & 511;
    const bool rope = (MODE == 0) && (mat < 2);
    const int head = sub >> 4;        // rope mapping: 16 blocks per head
    const int p0 = (sub & 15) << 2;   // pair base d = p0..p0+3
    const float* W = (mat == 0) ? W0 : ((mat == 1) ? W1 : W2);
    float* outp = out + (size_t)mat * (B * HID);

    const int tid = threadIdx.x;
    const int lane = tid & 63;
    const int wid = tid >> 6;
    const int b0 = wid << 3;

    float acc[8][8];
#pragma unroll
    for (int c = 0; c < 8; ++c)
#pragma unroll
        for (int j = 0; j < 8; ++j) acc[c][j] = 0.f;

    for (int k0 = 0; k0 < HID; k0 += 256) {
        __syncthreads();
#pragma unroll
        for (int i = 0; i < 2; ++i) {
            int idx = tid + (i << 8);
            int r = idx >> 6;
            int c4 = idx & 63;
            int cr = rope ? (head * 128 + p0 + (r & 3) + ((r >> 2) << 6))
                          : ((sub << 3) + r);
            float4 v = *reinterpret_cast<const float4*>(
                &W[(size_t)cr * HID + k0 + (c4 << 2)]);
            *reinterpret_cast<float4*>(&wt[r][c4 << 2]) = v;
        }
        __syncthreads();

        float4 hs4[8];
#pragma unroll
        for (int j = 0; j < 8; ++j)
            hs4[j] = *reinterpret_cast<const float4*>(
                &x[(size_t)(b0 + j) * HID + k0 + (lane << 2)]);

#pragma unroll
        for (int c = 0; c < 8; ++c) {
            float4 w4 = *reinterpret_cast<const float4*>(&wt[c][lane << 2]);
#pragma unroll
            for (int j = 0; j < 8; ++j) {
                acc[c][j] += w4.x * hs4[j].x;
                acc[c][j] += w4.y * hs4[j].y;
                acc[c][j] += w4.z * hs4[j].z;
                acc[c][j] += w4.w * hs4[j].w;
            }
        }
    }

    // ---- epilogue: per-c LDS transpose reduce (wave-private, no barrier) ----
    float res[8];
#pragma unroll
    for (int c = 0; c < 8; ++c) {
#pragma unroll
        for (int j = 0; j < 8; ++j) buf[wid][j][lane] = acc[c][j];
        __builtin_amdgcn_sched_barrier(0);
        const float* rp = &buf[wid][lane >> 3][(lane & 7) << 3];
        float4 a = *reinterpret_cast<const float4*>(rp);
        float4 bb = *reinterpret_cast<const float4*>(rp + 4);
        __builtin_amdgcn_sched_barrier(0);
        float s = ((a.x + a.y) + (a.z + a.w)) + ((bb.x + bb.y) + (bb.z + bb.w));
        s += __shfl_xor(s, 1, 64);
        s += __shfl_xor(s, 2, 64);
        s += __shfl_xor(s, 4, 64);
        res[c] = s;
    }

    const int jme = lane >> 3;
    const int cme = lane & 7;
    float myv;
    if (rope) {
        const float pf = (float)positions[b0 + jme];
        float ro[8];
#pragma unroll
        for (int cc = 0; cc < 4; ++cc) {
            float invf = exp2f(-(float)(p0 + cc) * 0.20762050593046013f); // 10000^(-d/64)
            float f = pf * invf;
            float cs = cosf(f), sn = sinf(f);
            ro[cc]     = res[cc] * cs - res[cc + 4] * sn;
            ro[cc + 4] = res[cc] * sn + res[cc + 4] * cs;
        }
        myv = ro[0];
#pragma unroll
        for (int cc = 1; cc < 8; ++cc) myv = (cme == cc) ? ro[cc] : myv;
    } else {
        myv = res[0];
#pragma unroll
        for (int cc = 1; cc < 8; ++cc) myv = (cme == cc) ? res[cc] : myv;
    }
    const int colw = rope ? (head * 128 + p0 + (cme & 3) + ((cme >> 2) << 6))
                          : ((sub << 3) + cme);
    outp[(size_t)(b0 + jme) * HID + colw] = myv;
}

// Flash-decode partial, h-grouped: block = (chunk c, batch b) covers ALL 32 heads
// of 128 slots. Per slot reads the full 16 KB [h][d] row contiguously.
// Thread t, fragment i in 0..3: head = 8i + (t>>5), dims (t&31)*4 .. +3.
__global__ __launch_bounds__(256) void attn_partial_kernel(
    const float* __restrict__ qkv,       // [3][B][HID]
    const float* __restrict__ k_cache,   // [NBLK*KBLK][H][D]
    const float* __restrict__ v_cache,
    const int* __restrict__ block_tables, // [B][MAXB]
    const int* __restrict__ context_lens,
    const int* __restrict__ positions,
    float* __restrict__ pm,              // [B*H][NCH]
    float* __restrict__ pl,              // [B*H][NCH]
    float* __restrict__ po)              // [B*H][NCH][D]
{
    const int c = blockIdx.x;
    const int b = blockIdx.y;
    const int L = context_lens[b];
    const int s0 = c << 7;
    if (s0 >= L) return;
    const int Lc = min(L - s0, CH);
    const int pos = positions[b];
    const int t = threadIdx.x;

    __shared__ float ps[32][CH + 1];    // scores/probs, padded
    __shared__ float mred[32], lred[32];
    __shared__ int btl[8];
    if (t < 8) btl[t] = block_tables[b * MAXB + (c << 3) + t];
    __syncthreads();

    const float* qb   = qkv + (size_t)b * HID;
    const float* knew = qkv + (size_t)(B * HID) + (size_t)b * HID;
    const float* vnew = qkv + (size_t)(2 * B * HID) + (size_t)b * HID;
    const float scale = 0.088388347648318447f; // 1/sqrt(128)

    const int hsub = t >> 5;   // 0..7
    const int hl5  = t & 31;

    const float4 q0 = *reinterpret_cast<const float4*>(qb + ((0 * 256 + t) << 2));
    const float4 q1 = *reinterpret_cast<const float4*>(qb + ((1 * 256 + t) << 2));
    const float4 q2 = *reinterpret_cast<const float4*>(qb + ((2 * 256 + t) << 2));
    const float4 q3 = *reinterpret_cast<const float4*>(qb + ((3 * 256 + t) << 2));

#define QK_BODY(s)                                                                 \
    {                                                                              \
        const int gs = s0 + (s);                                                   \
        const float* kb = (gs == pos) ? knew                                       \
            : k_cache + (size_t)(btl[(s) >> 4] * KBLK + (gs & 15)) * (H * D);      \
        float4 k0 = *reinterpret_cast<const float4*>(kb + ((0 * 256 + t) << 2));   \
        float4 k1 = *reinterpret_cast<const float4*>(kb + ((1 * 256 + t) << 2));   \
        float4 k2 = *reinterpret_cast<const float4*>(kb + ((2 * 256 + t) << 2));   \
        float4 k3 = *reinterpret_cast<const float4*>(kb + ((3 * 256 + t) << 2));   \
        float d0 = q0.x * k0.x + q0.y * k0.y + q0.z * k0.z + q0.w * k0.w;          \
        float d1 = q1.x * k1.x + q1.y * k1.y + q1.z * k1.z + q1.w * k1.w;          \
        float d2 = q2.x * k2.x + q2.y * k2.y + q2.z * k2.z + q2.w * k2.w;          \
        float d3 = q3.x * k3.x + q3.y * k3.y + q3.z * k3.z + q3.w * k3.w;          \
        _Pragma("unroll")                                                          \
        for (int m = 1; m <= 16; m <<= 1) {                                        \
            d0 += __shfl_xor(d0, m, 64);                                           \
            d1 += __shfl_xor(d1, m, 64);                                           \
            d2 += __shfl_xor(d2, m, 64);                                           \
            d3 += __shfl_xor(d3, m, 64);                                           \
        }                                                                          \
        if (hl5 == 0) {                                                            \
            ps[hsub][s]      = d0 * scale;                                         \
            ps[8 + hsub][s]  = d1 * scale;                                         \
            ps[16 + hsub][s] = d2 * scale;                                         \
            ps[24 + hsub][s] = d3 * scale;                                         \
        }                                                                          \
    }

    // ---- phase 1: K pass (16 KB contiguous per slot) ----
    {
        int s = 0;
        for (; s + 1 < Lc; s += 2) {
            QK_BODY(s);
            QK_BODY(s + 1);
        }
        if (s < Lc) QK_BODY(s);
    }
    __syncthreads();

    // ---- phase 2: per-head softmax. thread t: head hh=t>>3, slots so+8k ----
    const int hh = t >> 3;
    const int so = t & 7;
    float m = -1e30f;
#pragma unroll
    for (int k = 0; k < 16; ++k) {
        int s = so + (k << 3);
        if (s < Lc) m = fmaxf(m, ps[hh][s]);
    }
    m = fmaxf(m, __shfl_xor(m, 1, 64));
    m = fmaxf(m, __shfl_xor(m, 2, 64));
    m = fmaxf(m, __shfl_xor(m, 4, 64));
    if (so == 0) mred[hh] = m;
    __syncthreads();
    const float gm = mred[hh];
    float l = 0.f;
#pragma unroll
    for (int k = 0; k < 16; ++k) {
        int s = so + (k << 3);
        if (s < Lc) {
            float pv = __expf(ps[hh][s] - gm);
            ps[hh][s] = pv;
            l += pv;
        }
    }
    l += __shfl_xor(l, 1, 64);
    l += __shfl_xor(l, 2, 64);
    l += __shfl_xor(l, 4, 64);
    if (so == 0) lred[hh] = l;
    __syncthreads();

    // ---- phase 3: V pass. No shuffles: p broadcast from LDS. ----
    float4 o0 = {0.f, 0.f, 0.f, 0.f}, o1 = o0, o2 = o0, o3 = o0;

#define PV_BODY(s)                                                                 \
    {                                                                              \
        const int gs = s0 + (s);                                                   \
        const float* vb = (gs == pos) ? vnew                                       \
            : v_cache + (size_t)(btl[(s) >> 4] * KBLK + (gs & 15)) * (H * D);      \
        float4 v0 = *reinterpret_cast<const float4*>(vb + ((0 * 256 + t) << 2));   \
        float4 v1 = *reinterpret_cast<const float4*>(vb + ((1 * 256 + t) << 2));   \
        float4 v2 = *reinterpret_cast<const float4*>(vb + ((2 * 256 + t) << 2));   \
        float4 v3 = *reinterpret_cast<const float4*>(vb + ((3 * 256 + t) << 2));   \
        float pA = ps[hsub][s], pB = ps[8 + hsub][s];                              \
        float pC = ps[16 + hsub][s], pD = ps[24 + hsub][s];                        \
        o0.x += pA * v0.x; o0.y += pA * v0.y; o0.z += pA * v0.z; o0.w += pA * v0.w;\
        o1.x += pB * v1.x; o1.y += pB * v1.y; o1.z += pB * v1.z; o1.w += pB * v1.w;\
        o2.x += pC * v2.x; o2.y += pC * v2.y; o2.z += pC * v2.z; o2.w += pC * v2.w;\
        o3.x += pD * v3.x; o3.y += pD * v3.y; o3.z += pD * v3.z; o3.w += pD * v3.w;\
    }

    {
        int s = 0;
        for (; s + 1 < Lc; s += 2) {
            PV_BODY(s);
            PV_BODY(s + 1);
        }
        if (s < Lc) PV_BODY(s);
    }

    // ---- write partials ----
    const int dd = hl5 << 2;
    const size_t bh = (size_t)b * H;
    *reinterpret_cast<float4*>(&po[((bh + hsub)      * NCH + c) * D + dd]) = o0;
    *reinterpret_cast<float4*>(&po[((bh + 8 + hsub)  * NCH + c) * D + dd]) = o1;
    *reinterpret_cast<float4*>(&po[((bh + 16 + hsub) * NCH + c) * D + dd]) = o2;
    *reinterpret_cast<float4*>(&po[((bh + 24 + hsub) * NCH + c) * D + dd]) = o3;
    if (t < 32) {
        pm[(bh + t) * NCH + c] = mred[t];
        pl[(bh + t) * NCH + c] = lred[t];
    }
#undef QK_BODY
#undef PV_BODY
}

// Combine partials. grid = B*H, block = 128.
__global__ __launch_bounds__(128) void attn_combine_kernel(
    const float* __restrict__ pm, const float* __restrict__ pl,
    const float* __restrict__ po, const int* __restrict__ context_lens,
    float* __restrict__ attn_out)
{
    const int bh = blockIdx.x;
    const int b = bh >> 5;
    const int tid = threadIdx.x;
    const int nc = (context_lens[b] + CH - 1) >> 7;

    float m = -1e30f;
    for (int c = 0; c < nc; ++c) m = fmaxf(m, pm[bh * NCH + c]);
    float wsum = 0.f, o = 0.f;
    for (int c = 0; c < nc; ++c) {
        float wc = __expf(pm[bh * NCH + c] - m);
        wsum += wc * pl[bh * NCH + c];
        o += wc * po[((size_t)bh * NCH + c) * D + tid];
    }
    attn_out[(size_t)bh * D + tid] = o / wsum;
}

extern "C" void kernel_launch(void* const* d_in, const int* in_sizes, int n_in,
                              void* d_out, int out_size, void* d_ws, size_t ws_size,
                              hipStream_t stream) {
    const float* hs        = (const float*)d_in[0];
    const float* k_cache   = (const float*)d_in[1];
    const float* v_cache   = (const float*)d_in[2];
    const float* Wq        = (const float*)d_in[3];
    const float* Wk        = (const float*)d_in[4];
    const float* Wv        = (const float*)d_in[5];
    const float* Wo        = (const float*)d_in[6];
    const int*   positions = (const int*)d_in[7];
    const int*   block_tables = (const int*)d_in[9];
    const int*   context_lens = (const int*)d_in[10];
    float* out = (float*)d_out;

    float* qkv     = (float*)d_ws;                         // [3][B][HID] (q,k pre-roped)
    float* attn_ws = qkv + (size_t)3 * B * HID;            // [B][HID]
    float* pm      = attn_ws + (size_t)B * HID;            // [B*H][NCH]
    float* pl      = pm + (size_t)B * H * NCH;             // [B*H][NCH]
    float* po      = pl + (size_t)B * H * NCH;             // [B*H][NCH][D]

    gemv_kernel<0><<<dim3(3 * 512), 256, 0, stream>>>(Wq, Wk, Wv, hs, positions, qkv);
    attn_partial_kernel<<<dim3(NCH, B), 256, 0, stream>>>(
        qkv, k_cache, v_cache, block_tables, context_lens, positions, pm, pl, po);
    attn_combine_kernel<<<dim3(B * H), 128, 0, stream>>>(pm, pl, po, context_lens, attn_ws);
    gemv_kernel<1><<<dim3(512), 256, 0, stream>>>(Wo, Wo, Wo, attn_ws, positions, out);
}

// Round 6
// 311.223 us; speedup vs baseline: 1.2452x; 1.2452x over previous
//
#include <hip/hip_runtime.h>
#include <math.h>

#define HID 4096
#define B 32
#define H 32
#define D 128
#define KBLK 16
#define MAXB 64

// out[b][n] = sum_k x[b][k] * W[n][k]
// MODE 0: QKV (grid 3*512; mats 0,1 get fused RoPE, pair-column mapping).
// MODE 1: single matrix, no rope (grid 512).
template <int MODE>
__global__ __launch_bounds__(256) void gemv_kernel(
    const float* __restrict__ W0, const float* __restrict__ W1, const float* __restrict__ W2,
    const float* __restrict__ x, const int* __restrict__ positions, float* __restrict__ out)
{
    __shared__ float wt[8][256];
    __shared__ float buf[4][8][66];   // per-wave transpose-reduce scratch
    const int bid = blockIdx.x;
    const int mat = (MODE == 0) ? (bid >> 9) : 0;
    const int sub = bid & 511;
    const bool rope = (MODE == 0) && (mat < 2);
    const int head = sub >> 4;        // rope mapping: 16 blocks per head
    const int p0 = (sub & 15) << 2;   // pair base d = p0..p0+3
    const float* W = (mat == 0) ? W0 : ((mat == 1) ? W1 : W2);
    float* outp = out + (size_t)mat * (B * HID);

    const int tid = threadIdx.x;
    const int lane = tid & 63;
    const int wid = tid >> 6;
    const int b0 = wid << 3;

    float acc[8][8];
#pragma unroll
    for (int c = 0; c < 8; ++c)
#pragma unroll
        for (int j = 0; j < 8; ++j) acc[c][j] = 0.f;

    for (int k0 = 0; k0 < HID; k0 += 256) {
        __syncthreads();
#pragma unroll
        for (int i = 0; i < 2; ++i) {
            int idx = tid + (i << 8);
            int r = idx >> 6;
            int c4 = idx & 63;
            int cr = rope ? (head * 128 + p0 + (r & 3) + ((r >> 2) << 6))
                          : ((sub << 3) + r);
            float4 v = *reinterpret_cast<const float4*>(
                &W[(size_t)cr * HID + k0 + (c4 << 2)]);
            *reinterpret_cast<float4*>(&wt[r][c4 << 2]) = v;
        }
        __syncthreads();

        float4 hs4[8];
#pragma unroll
        for (int j = 0; j < 8; ++j)
            hs4[j] = *reinterpret_cast<const float4*>(
                &x[(size_t)(b0 + j) * HID + k0 + (lane << 2)]);

#pragma unroll
        for (int c = 0; c < 8; ++c) {
            float4 w4 = *reinterpret_cast<const float4*>(&wt[c][lane << 2]);
#pragma unroll
            for (int j = 0; j < 8; ++j) {
                acc[c][j] += w4.x * hs4[j].x;
                acc[c][j] += w4.y * hs4[j].y;
                acc[c][j] += w4.z * hs4[j].z;
                acc[c][j] += w4.w * hs4[j].w;
            }
        }
    }

    // ---- epilogue: per-c LDS transpose reduce (wave-private, no barrier) ----
    float res[8];
#pragma unroll
    for (int c = 0; c < 8; ++c) {
#pragma unroll
        for (int j = 0; j < 8; ++j) buf[wid][j][lane] = acc[c][j];
        __builtin_amdgcn_sched_barrier(0);
        const float* rp = &buf[wid][lane >> 3][(lane & 7) << 3];
        float4 a = *reinterpret_cast<const float4*>(rp);
        float4 bb = *reinterpret_cast<const float4*>(rp + 4);
        __builtin_amdgcn_sched_barrier(0);
        float s = ((a.x + a.y) + (a.z + a.w)) + ((bb.x + bb.y) + (bb.z + bb.w));
        s += __shfl_xor(s, 1, 64);
        s += __shfl_xor(s, 2, 64);
        s += __shfl_xor(s, 4, 64);
        res[c] = s;
    }

    const int jme = lane >> 3;
    const int cme = lane & 7;
    float myv;
    if (rope) {
        const float pf = (float)positions[b0 + jme];
        float ro[8];
#pragma unroll
        for (int cc = 0; cc < 4; ++cc) {
            float invf = exp2f(-(float)(p0 + cc) * 0.20762050593046013f); // 10000^(-d/64)
            float f = pf * invf;
            float cs = cosf(f), sn = sinf(f);
            ro[cc]     = res[cc] * cs - res[cc + 4] * sn;
            ro[cc + 4] = res[cc] * sn + res[cc + 4] * cs;
        }
        myv = ro[0];
#pragma unroll
        for (int cc = 1; cc < 8; ++cc) myv = (cme == cc) ? ro[cc] : myv;
    } else {
        myv = res[0];
#pragma unroll
        for (int cc = 1; cc < 8; ++cc) myv = (cme == cc) ? res[cc] : myv;
    }
    const int colw = rope ? (head * 128 + p0 + (cme & 3) + ((cme >> 2) << 6))
                          : ((sub << 3) + cme);
    outp[(size_t)(b0 + jme) * HID + colw] = myv;
}

// Flash-decode partial, h-grouped, one KV block (16 slots) per CTA.
// grid (MAXB, B) = 2048 blocks. Per slot reads the full 16 KB [h][d] row
// contiguously. Thread t, fragment i: head = 8i + (t>>5), dims (t&31)*4..+3.
__global__ __launch_bounds__(256) void attn_partial_kernel(
    const float* __restrict__ qkv,       // [3][B][HID]
    const float* __restrict__ k_cache,   // [NBLK*KBLK][H][D]
    const float* __restrict__ v_cache,
    const int* __restrict__ block_tables, // [B][MAXB]
    const int* __restrict__ context_lens,
    const int* __restrict__ positions,
    float* __restrict__ pm,              // [B*H][MAXB]
    float* __restrict__ pl,              // [B*H][MAXB]
    float* __restrict__ po)              // [B*H][MAXB][D]
{
    const int c = blockIdx.x;
    const int b = blockIdx.y;
    const int L = context_lens[b];
    const int s0 = c << 4;
    if (s0 >= L) return;
    const int Lc = min(L - s0, KBLK);
    const int pos = positions[b];
    const int t = threadIdx.x;

    __shared__ float ps[32][17];        // [head][slot], padded
    __shared__ float mred[32], lred[32];

    const int bt0 = block_tables[b * MAXB + c];     // block-uniform -> scalar
    const float* kbase = k_cache + (size_t)bt0 * (KBLK * H * D);
    const float* vbase = v_cache + (size_t)bt0 * (KBLK * H * D);
    const bool haspos = ((pos >> 4) == c);
    const int spos = pos & 15;

    const float* qb   = qkv + (size_t)b * HID;
    const float* knew = qkv + (size_t)(B * HID) + (size_t)b * HID;
    const float* vnew = qkv + (size_t)(2 * B * HID) + (size_t)b * HID;
    const float scale = 0.088388347648318447f; // 1/sqrt(128)

    const int hsub = t >> 5;   // 0..7
    const int hl5  = t & 31;

    const float4 q0 = *reinterpret_cast<const float4*>(qb + ((0 * 256 + t) << 2));
    const float4 q1 = *reinterpret_cast<const float4*>(qb + ((1 * 256 + t) << 2));
    const float4 q2 = *reinterpret_cast<const float4*>(qb + ((2 * 256 + t) << 2));
    const float4 q3 = *reinterpret_cast<const float4*>(qb + ((3 * 256 + t) << 2));

#define QK_BODY(s)                                                                 \
    {                                                                              \
        const float* kb = (haspos && (s) == spos) ? knew                           \
                                                  : kbase + (size_t)(s) * (H * D); \
        float4 k0 = *reinterpret_cast<const float4*>(kb + ((0 * 256 + t) << 2));   \
        float4 k1 = *reinterpret_cast<const float4*>(kb + ((1 * 256 + t) << 2));   \
        float4 k2 = *reinterpret_cast<const float4*>(kb + ((2 * 256 + t) << 2));   \
        float4 k3 = *reinterpret_cast<const float4*>(kb + ((3 * 256 + t) << 2));   \
        float d0 = q0.x * k0.x + q0.y * k0.y + q0.z * k0.z + q0.w * k0.w;          \
        float d1 = q1.x * k1.x + q1.y * k1.y + q1.z * k1.z + q1.w * k1.w;          \
        float d2 = q2.x * k2.x + q2.y * k2.y + q2.z * k2.z + q2.w * k2.w;          \
        float d3 = q3.x * k3.x + q3.y * k3.y + q3.z * k3.z + q3.w * k3.w;          \
        _Pragma("unroll")                                                          \
        for (int m = 1; m <= 16; m <<= 1) {                                        \
            d0 += __shfl_xor(d0, m, 64);                                           \
            d1 += __shfl_xor(d1, m, 64);                                           \
            d2 += __shfl_xor(d2, m, 64);                                           \
            d3 += __shfl_xor(d3, m, 64);                                           \
        }                                                                          \
        if (hl5 == 0) {                                                            \
            ps[hsub][s]      = d0 * scale;                                         \
            ps[8 + hsub][s]  = d1 * scale;                                         \
            ps[16 + hsub][s] = d2 * scale;                                         \
            ps[24 + hsub][s] = d3 * scale;                                         \
        }                                                                          \
    }

    // ---- phase 1: K pass (16 KB contiguous per slot) ----
    if (Lc == KBLK) {
#pragma unroll 4
        for (int s = 0; s < KBLK; ++s) QK_BODY(s);
    } else {
        for (int s = 0; s < Lc; ++s) QK_BODY(s);
    }
    __syncthreads();

    // ---- phase 2: per-head softmax over <=16 slots ----
    const int hh = t >> 3;   // head 0..31
    const int so = t & 7;
    float m = -1e30f;
    if (so < Lc) m = ps[hh][so];
    if (so + 8 < Lc) m = fmaxf(m, ps[hh][so + 8]);
    m = fmaxf(m, __shfl_xor(m, 1, 64));
    m = fmaxf(m, __shfl_xor(m, 2, 64));
    m = fmaxf(m, __shfl_xor(m, 4, 64));
    if (so == 0) mred[hh] = m;
    __syncthreads();
    const float gm = mred[hh];
    float l = 0.f;
    if (so < Lc) { float pv = __expf(ps[hh][so] - gm); ps[hh][so] = pv; l += pv; }
    if (so + 8 < Lc) { float pv = __expf(ps[hh][so + 8] - gm); ps[hh][so + 8] = pv; l += pv; }
    l += __shfl_xor(l, 1, 64);
    l += __shfl_xor(l, 2, 64);
    l += __shfl_xor(l, 4, 64);
    if (so == 0) lred[hh] = l;
    __syncthreads();   // ps[] = probs visible to all

    // ---- phase 3: V pass. No shuffles: p broadcast from LDS. ----
    float4 o0 = {0.f, 0.f, 0.f, 0.f}, o1 = o0, o2 = o0, o3 = o0;

#define PV_BODY(s)                                                                 \
    {                                                                              \
        const float* vb = (haspos && (s) == spos) ? vnew                           \
                                                  : vbase + (size_t)(s) * (H * D); \
        float4 v0 = *reinterpret_cast<const float4*>(vb + ((0 * 256 + t) << 2));   \
        float4 v1 = *reinterpret_cast<const float4*>(vb + ((1 * 256 + t) << 2));   \
        float4 v2 = *reinterpret_cast<const float4*>(vb + ((2 * 256 + t) << 2));   \
        float4 v3 = *reinterpret_cast<const float4*>(vb + ((3 * 256 + t) << 2));   \
        float pA = ps[hsub][s], pB = ps[8 + hsub][s];                              \
        float pC = ps[16 + hsub][s], pD = ps[24 + hsub][s];                        \
        o0.x += pA * v0.x; o0.y += pA * v0.y; o0.z += pA * v0.z; o0.w += pA * v0.w;\
        o1.x += pB * v1.x; o1.y += pB * v1.y; o1.z += pB * v1.z; o1.w += pB * v1.w;\
        o2.x += pC * v2.x; o2.y += pC * v2.y; o2.z += pC * v2.z; o2.w += pC * v2.w;\
        o3.x += pD * v3.x; o3.y += pD * v3.y; o3.z += pD * v3.z; o3.w += pD * v3.w;\
    }

    if (Lc == KBLK) {
#pragma unroll 4
        for (int s = 0; s < KBLK; ++s) PV_BODY(s);
    } else {
        for (int s = 0; s < Lc; ++s) PV_BODY(s);
    }

    // ---- write partials ----
    const int dd = hl5 << 2;
    const size_t bh = (size_t)b * H;
    *reinterpret_cast<float4*>(&po[((bh + hsub)      * MAXB + c) * D + dd]) = o0;
    *reinterpret_cast<float4*>(&po[((bh + 8 + hsub)  * MAXB + c) * D + dd]) = o1;
    *reinterpret_cast<float4*>(&po[((bh + 16 + hsub) * MAXB + c) * D + dd]) = o2;
    *reinterpret_cast<float4*>(&po[((bh + 24 + hsub) * MAXB + c) * D + dd]) = o3;
    if (t < 32) {
        pm[(bh + t) * MAXB + c] = mred[t];
        pl[(bh + t) * MAXB + c] = lred[t];
    }
#undef QK_BODY
#undef PV_BODY
}

// Combine partials. grid = B*H, block = 128.
__global__ __launch_bounds__(128) void attn_combine_kernel(
    const float* __restrict__ pm, const float* __restrict__ pl,
    const float* __restrict__ po, const int* __restrict__ context_lens,
    float* __restrict__ attn_out)
{
    const int bh = blockIdx.x;
    const int b = bh >> 5;
    const int tid = threadIdx.x;
    const int nc = (context_lens[b] + KBLK - 1) >> 4;

    float m = -1e30f;
    for (int c = 0; c < nc; ++c) m = fmaxf(m, pm[bh * MAXB + c]);
    float wsum = 0.f, o = 0.f;
    for (int c = 0; c < nc; ++c) {
        float wc = __expf(pm[bh * MAXB + c] - m);
        wsum += wc * pl[bh * MAXB + c];
        o += wc * po[((size_t)bh * MAXB + c) * D + tid];
    }
    attn_out[(size_t)bh * D + tid] = o / wsum;
}

extern "C" void kernel_launch(void* const* d_in, const int* in_sizes, int n_in,
                              void* d_out, int out_size, void* d_ws, size_t ws_size,
                              hipStream_t stream) {
    const float* hs        = (const float*)d_in[0];
    const float* k_cache   = (const float*)d_in[1];
    const float* v_cache   = (const float*)d_in[2];
    const float* Wq        = (const float*)d_in[3];
    const float* Wk        = (const float*)d_in[4];
    const float* Wv        = (const float*)d_in[5];
    const float* Wo        = (const float*)d_in[6];
    const int*   positions = (const int*)d_in[7];
    const int*   block_tables = (const int*)d_in[9];
    const int*   context_lens = (const int*)d_in[10];
    float* out = (float*)d_out;

    float* qkv     = (float*)d_ws;                         // [3][B][HID] (q,k pre-roped)
    float* attn_ws = qkv + (size_t)3 * B * HID;            // [B][HID]
    float* pm      = attn_ws + (size_t)B * HID;            // [B*H][MAXB]
    float* pl      = pm + (size_t)B * H * MAXB;            // [B*H][MAXB]
    float* po      = pl + (size_t)B * H * MAXB;            // [B*H][MAXB][D]

    gemv_kernel<0><<<dim3(3 * 512), 256, 0, stream>>>(Wq, Wk, Wv, hs, positions, qkv);
    attn_partial_kernel<<<dim3(MAXB, B), 256, 0, stream>>>(
        qkv, k_cache, v_cache, block_tables, context_lens, positions, pm, pl, po);
    attn_combine_kernel<<<dim3(B * H), 128, 0, stream>>>(pm, pl, po, context_lens, attn_ws);
    gemv_kernel<1><<<dim3(512), 256, 0, stream>>>(Wo, Wo, Wo, attn_ws, positions, out);
}

// Round 7
// 245.434 us; speedup vs baseline: 1.5790x; 1.2681x over previous
//
#include <hip/hip_runtime.h>
#include <math.h>

#define HID 4096
#define B 32
#define H 32
#define D 128
#define KBLK 16
#define MAXB 64
#define CHUNK 256
#define NCHUNK 4

typedef float f4 __attribute__((ext_vector_type(4)));
typedef float f2 __attribute__((ext_vector_type(2)));
#define NT_LD4(p) __builtin_nontemporal_load(reinterpret_cast<const f4*>(p))
#define NT_LD2(p) __builtin_nontemporal_load(reinterpret_cast<const f2*>(p))

// out[b][n] = sum_k x[b][k] * W[n][k]
// MODE 0: QKV (grid 3*512; mats 0,1 get fused RoPE, pair-column mapping).
// MODE 1: single matrix, no rope (grid 512).
template <int MODE>
__global__ __launch_bounds__(256) void gemv_kernel(
    const float* __restrict__ W0, const float* __restrict__ W1, const float* __restrict__ W2,
    const float* __restrict__ x, const int* __restrict__ positions, float* __restrict__ out)
{
    __shared__ float wt[8][256];
    __shared__ float buf[4][8][66];   // per-wave transpose-reduce scratch
    const int bid = blockIdx.x;
    const int mat = (MODE == 0) ? (bid >> 9) : 0;
    const int sub = bid & 511;
    const bool rope = (MODE == 0) && (mat < 2);
    const int head = sub >> 4;        // rope mapping: 16 blocks per head
    const int p0 = (sub & 15) << 2;   // pair base d = p0..p0+3
    const float* W = (mat == 0) ? W0 : ((mat == 1) ? W1 : W2);
    float* outp = out + (size_t)mat * (B * HID);

    const int tid = threadIdx.x;
    const int lane = tid & 63;
    const int wid = tid >> 6;
    const int b0 = wid << 3;

    float acc[8][8];
#pragma unroll
    for (int c = 0; c < 8; ++c)
#pragma unroll
        for (int j = 0; j < 8; ++j) acc[c][j] = 0.f;

    for (int k0 = 0; k0 < HID; k0 += 256) {
        __syncthreads();
#pragma unroll
        for (int i = 0; i < 2; ++i) {
            int idx = tid + (i << 8);
            int r = idx >> 6;
            int c4 = idx & 63;
            int cr = rope ? (head * 128 + p0 + (r & 3) + ((r >> 2) << 6))
                          : ((sub << 3) + r);
            f4 v = NT_LD4(&W[(size_t)cr * HID + k0 + (c4 << 2)]);   // W: stream, bypass L2
            *reinterpret_cast<f4*>(&wt[r][c4 << 2]) = v;
        }
        __syncthreads();

        float4 hs4[8];
#pragma unroll
        for (int j = 0; j < 8; ++j)
            hs4[j] = *reinterpret_cast<const float4*>(
                &x[(size_t)(b0 + j) * HID + k0 + (lane << 2)]);     // x: cached (reused)

#pragma unroll
        for (int c = 0; c < 8; ++c) {
            float4 w4 = *reinterpret_cast<const float4*>(&wt[c][lane << 2]);
#pragma unroll
            for (int j = 0; j < 8; ++j) {
                acc[c][j] += w4.x * hs4[j].x;
                acc[c][j] += w4.y * hs4[j].y;
                acc[c][j] += w4.z * hs4[j].z;
                acc[c][j] += w4.w * hs4[j].w;
            }
        }
    }

    // ---- epilogue: per-c LDS transpose reduce (wave-private, no barrier) ----
    float res[8];
#pragma unroll
    for (int c = 0; c < 8; ++c) {
#pragma unroll
        for (int j = 0; j < 8; ++j) buf[wid][j][lane] = acc[c][j];
        __builtin_amdgcn_sched_barrier(0);
        const float* rp = &buf[wid][lane >> 3][(lane & 7) << 3];
        float4 a = *reinterpret_cast<const float4*>(rp);
        float4 bb = *reinterpret_cast<const float4*>(rp + 4);
        __builtin_amdgcn_sched_barrier(0);
        float s = ((a.x + a.y) + (a.z + a.w)) + ((bb.x + bb.y) + (bb.z + bb.w));
        s += __shfl_xor(s, 1, 64);
        s += __shfl_xor(s, 2, 64);
        s += __shfl_xor(s, 4, 64);
        res[c] = s;
    }

    const int jme = lane >> 3;
    const int cme = lane & 7;
    float myv;
    if (rope) {
        const float pf = (float)positions[b0 + jme];
        float ro[8];
#pragma unroll
        for (int cc = 0; cc < 4; ++cc) {
            float invf = exp2f(-(float)(p0 + cc) * 0.20762050593046013f); // 10000^(-d/64)
            float f = pf * invf;
            float cs = cosf(f), sn = sinf(f);
            ro[cc]     = res[cc] * cs - res[cc + 4] * sn;
            ro[cc + 4] = res[cc] * sn + res[cc + 4] * cs;
        }
        myv = ro[0];
#pragma unroll
        for (int cc = 1; cc < 8; ++cc) myv = (cme == cc) ? ro[cc] : myv;
    } else {
        myv = res[0];
#pragma unroll
        for (int cc = 1; cc < 8; ++cc) myv = (cme == cc) ? res[cc] : myv;
    }
    const int colw = rope ? (head * 128 + p0 + (cme & 3) + ((cme >> 2) << 6))
                          : ((sub << 3) + cme);
    outp[(size_t)(b0 + jme) * HID + colw] = myv;
}

// Flash-decode partial: grid (H, NCHUNK, B), block = 256. q/k in qkv are pre-roped.
// K/V reads are nontemporal (pure stream, keep L2 for q/sc/partials).
__global__ __launch_bounds__(256) void attn_partial_kernel(
    const float* __restrict__ qkv,       // [3][B][HID]
    const float* __restrict__ k_cache,   // [NBLK*KBLK][H][D]
    const float* __restrict__ v_cache,
    const int* __restrict__ block_tables, // [B][MAXB]
    const int* __restrict__ context_lens,
    const int* __restrict__ positions,
    float* __restrict__ pm,              // [B*H][NCHUNK]
    float* __restrict__ pl,              // [B*H][NCHUNK]
    float* __restrict__ po)              // [B*H][NCHUNK][D]
{
    const int h = blockIdx.x;
    const int c = blockIdx.y;
    const int b = blockIdx.z;
    const int L = context_lens[b];
    const int s0 = c << 8;
    if (s0 >= L) return;
    const int Lc = min(L - s0, CHUNK);
    const int pos = positions[b];
    const int tid = threadIdx.x;

    __shared__ float sc[CHUNK];
    __shared__ float red[8];
    __shared__ int btl[16];
    __shared__ float o4[4][D];

    if (tid < 16) btl[tid] = block_tables[b * MAXB + (c << 4) + tid];
    __syncthreads();

    const float* qptr = qkv + (size_t)b * HID + h * D;
    const float* knew = qkv + (size_t)(B * HID) + (size_t)b * HID + h * D;
    const float* vnew = qkv + (size_t)(2 * B * HID) + (size_t)b * HID + h * D;
    const float scale = 0.088388347648318447f; // 1/sqrt(128)

    // ---- phase 1: scores, one s per half-wave, 4 rows in flight ----
    const int hw = tid >> 5;
    const int hl = tid & 31;
    const float4 qv = *reinterpret_cast<const float4*>(qptr + (hl << 2));

    int i = hw;
    for (; i + 24 < Lc; i += 32) {
        const int sA = s0 + i, sB = sA + 8, sC = sA + 16, sD = sA + 24;
        const float* kp0 = (sA == pos) ? knew
            : k_cache + ((size_t)(btl[i >> 4] * KBLK + (sA & 15)) * H + h) * D;
        const float* kp1 = (sB == pos) ? knew
            : k_cache + ((size_t)(btl[(i + 8) >> 4] * KBLK + (sB & 15)) * H + h) * D;
        const float* kp2 = (sC == pos) ? knew
            : k_cache + ((size_t)(btl[(i + 16) >> 4] * KBLK + (sC & 15)) * H + h) * D;
        const float* kp3 = (sD == pos) ? knew
            : k_cache + ((size_t)(btl[(i + 24) >> 4] * KBLK + (sD & 15)) * H + h) * D;
        f4 k0 = NT_LD4(kp0 + (hl << 2));
        f4 k1 = NT_LD4(kp1 + (hl << 2));
        f4 k2 = NT_LD4(kp2 + (hl << 2));
        f4 k3 = NT_LD4(kp3 + (hl << 2));
        float d0 = qv.x * k0[0] + qv.y * k0[1] + qv.z * k0[2] + qv.w * k0[3];
        float d1 = qv.x * k1[0] + qv.y * k1[1] + qv.z * k1[2] + qv.w * k1[3];
        float d2 = qv.x * k2[0] + qv.y * k2[1] + qv.z * k2[2] + qv.w * k2[3];
        float d3 = qv.x * k3[0] + qv.y * k3[1] + qv.z * k3[2] + qv.w * k3[3];
#pragma unroll
        for (int m = 16; m; m >>= 1) {
            d0 += __shfl_xor(d0, m, 64);
            d1 += __shfl_xor(d1, m, 64);
            d2 += __shfl_xor(d2, m, 64);
            d3 += __shfl_xor(d3, m, 64);
        }
        if (hl == 0) {
            sc[i] = d0 * scale; sc[i + 8] = d1 * scale;
            sc[i + 16] = d2 * scale; sc[i + 24] = d3 * scale;
        }
    }
    for (; i < Lc; i += 8) {
        const int sA = s0 + i;
        const float* kp = (sA == pos) ? knew
            : k_cache + ((size_t)(btl[i >> 4] * KBLK + (sA & 15)) * H + h) * D;
        f4 k0 = NT_LD4(kp + (hl << 2));
        float d0 = qv.x * k0[0] + qv.y * k0[1] + qv.z * k0[2] + qv.w * k0[3];
#pragma unroll
        for (int m = 16; m; m >>= 1) d0 += __shfl_xor(d0, m, 64);
        if (hl == 0) sc[i] = d0 * scale;
    }
    for (; i < CHUNK; i += 8)
        if (hl == 0) sc[i] = -1e30f;
    __syncthreads();

    // ---- phase 2: chunk-local softmax (one element per thread) ----
    const int w = tid >> 6;
    const float xv = sc[tid];
    float m = xv;
#pragma unroll
    for (int mm = 32; mm; mm >>= 1) m = fmaxf(m, __shfl_xor(m, mm, 64));
    if ((tid & 63) == 0) red[w] = m;
    __syncthreads();
    const float gm = fmaxf(fmaxf(red[0], red[1]), fmaxf(red[2], red[3]));

    float p = (xv > -1e29f) ? __expf(xv - gm) : 0.f;
    sc[tid] = p;
    float l = p;
#pragma unroll
    for (int mm = 32; mm; mm >>= 1) l += __shfl_xor(l, mm, 64);
    if ((tid & 63) == 0) red[4 + w] = l;
    __syncthreads();
    const float gl = red[4] + red[5] + red[6] + red[7];

    // ---- phase 3: partial O = P.V ; one s per wave, 4 rows in flight ----
    const int l2 = (tid & 63) << 1;
    float accx = 0.f, accy = 0.f;
    i = w;
    for (; i + 12 < Lc; i += 16) {
        const int sA = s0 + i, sB = sA + 4, sC = sA + 8, sD = sA + 12;
        const float* vp0 = (sA == pos) ? vnew
            : v_cache + ((size_t)(btl[i >> 4] * KBLK + (sA & 15)) * H + h) * D;
        const float* vp1 = (sB == pos) ? vnew
            : v_cache + ((size_t)(btl[(i + 4) >> 4] * KBLK + (sB & 15)) * H + h) * D;
        const float* vp2 = (sC == pos) ? vnew
            : v_cache + ((size_t)(btl[(i + 8) >> 4] * KBLK + (sC & 15)) * H + h) * D;
        const float* vp3 = (sD == pos) ? vnew
            : v_cache + ((size_t)(btl[(i + 12) >> 4] * KBLK + (sD & 15)) * H + h) * D;
        f2 v0 = NT_LD2(vp0 + l2);
        f2 v1 = NT_LD2(vp1 + l2);
        f2 v2 = NT_LD2(vp2 + l2);
        f2 v3 = NT_LD2(vp3 + l2);
        float p0 = sc[i], p1 = sc[i + 4], p2 = sc[i + 8], p3 = sc[i + 12];
        accx += p0 * v0[0]; accy += p0 * v0[1];
        accx += p1 * v1[0]; accy += p1 * v1[1];
        accx += p2 * v2[0]; accy += p2 * v2[1];
        accx += p3 * v3[0]; accy += p3 * v3[1];
    }
    for (; i < Lc; i += 4) {
        const float* vp = (s0 + i == pos) ? vnew
            : v_cache + ((size_t)(btl[i >> 4] * KBLK + ((s0 + i) & 15)) * H + h) * D;
        f2 v0 = NT_LD2(vp + l2);
        float p0 = sc[i];
        accx += p0 * v0[0]; accy += p0 * v0[1];
    }
    o4[w][l2] = accx;
    o4[w][l2 + 1] = accy;
    __syncthreads();

    const int bh = b * H + h;
    if (tid < D) {
        float o = o4[0][tid] + o4[1][tid] + o4[2][tid] + o4[3][tid];
        po[((size_t)bh * NCHUNK + c) * D + tid] = o;
    } else if (tid == D) {
        pm[bh * NCHUNK + c] = gm;
        pl[bh * NCHUNK + c] = gl;
    }
}

// Combine partials. grid = B*H, block = 128.
__global__ __launch_bounds__(128) void attn_combine_kernel(
    const float* __restrict__ pm, const float* __restrict__ pl,
    const float* __restrict__ po, const int* __restrict__ context_lens,
    float* __restrict__ attn_out)
{
    const int bh = blockIdx.x;
    const int b = bh >> 5;
    const int tid = threadIdx.x;
    const int nc = (context_lens[b] + CHUNK - 1) >> 8;

    float m = -1e30f;
    for (int c = 0; c < nc; ++c) m = fmaxf(m, pm[bh * NCHUNK + c]);
    float wsum = 0.f, o = 0.f;
    for (int c = 0; c < nc; ++c) {
        float wc = __expf(pm[bh * NCHUNK + c] - m);
        wsum += wc * pl[bh * NCHUNK + c];
        o += wc * po[((size_t)bh * NCHUNK + c) * D + tid];
    }
    attn_out[(size_t)bh * D + tid] = o / wsum;
}

extern "C" void kernel_launch(void* const* d_in, const int* in_sizes, int n_in,
                              void* d_out, int out_size, void* d_ws, size_t ws_size,
                              hipStream_t stream) {
    const float* hs        = (const float*)d_in[0];
    const float* k_cache   = (const float*)d_in[1];
    const float* v_cache   = (const float*)d_in[2];
    const float* Wq        = (const float*)d_in[3];
    const float* Wk        = (const float*)d_in[4];
    const float* Wv        = (const float*)d_in[5];
    const float* Wo        = (const float*)d_in[6];
    const int*   positions = (const int*)d_in[7];
    const int*   block_tables = (const int*)d_in[9];
    const int*   context_lens = (const int*)d_in[10];
    float* out = (float*)d_out;

    float* qkv     = (float*)d_ws;                         // [3][B][HID] (q,k pre-roped)
    float* attn_ws = qkv + (size_t)3 * B * HID;            // [B][HID]
    float* pm      = attn_ws + (size_t)B * HID;            // [B*H][NCHUNK]
    float* pl      = pm + (size_t)B * H * NCHUNK;          // [B*H][NCHUNK]
    float* po      = pl + (size_t)B * H * NCHUNK;          // [B*H][NCHUNK][D]

    gemv_kernel<0><<<dim3(3 * 512), 256, 0, stream>>>(Wq, Wk, Wv, hs, positions, qkv);
    attn_partial_kernel<<<dim3(H, NCHUNK, B), 256, 0, stream>>>(
        qkv, k_cache, v_cache, block_tables, context_lens, positions, pm, pl, po);
    attn_combine_kernel<<<dim3(B * H), 128, 0, stream>>>(pm, pl, po, context_lens, attn_ws);
    gemv_kernel<1><<<dim3(512), 256, 0, stream>>>(Wo, Wo, Wo, attn_ws, positions, out);
}